// Round 1
// baseline (993.192 us; speedup 1.0000x reference)
//
#include <hip/hip_runtime.h>

#define N_NODES 50000
#define N_EDGES 800000
#define IN_DIM 256
#define OUT_DIM 64
#define HEADS 4
#define HD 256          // HEADS*OUT_DIM
#define P_L 0.1f
#define TILE_N 16
#define CN 4

// ---------------- precompute: fold W_att/b_att into W_g ----------------
// v_dst[h*64+d] = sum_e W_att[h][d][e] * W_g[h][e]        (first half)
// v_src[h*64+d] = sum_e W_att[h][d][e] * W_g[h][64+e]     (second half)
// c_dst[h] = sum_e b_att[h][e]*W_g[h][e];  c_src analogous
__global__ __launch_bounds__(256) void precompute_kernel(
    const float* __restrict__ W_att, const float* __restrict__ b_att,
    const float* __restrict__ W_g,
    float* __restrict__ v_dst, float* __restrict__ v_src,
    float* __restrict__ c_dst, float* __restrict__ c_src) {
    int t = threadIdx.x;          // 0..255
    int h = t >> 6, dd = t & 63;
    float sd = 0.f, ss = 0.f;
    for (int e = 0; e < 64; ++e) {
        float w = W_att[h * 4096 + dd * 64 + e];
        sd += w * W_g[h * 128 + e];
        ss += w * W_g[h * 128 + 64 + e];
    }
    v_dst[t] = sd;
    v_src[t] = ss;
    if (dd == 0) {
        float cd = 0.f, cs = 0.f;
        for (int e = 0; e < 64; ++e) {
            float b = b_att[h * 64 + e];
            cd += b * W_g[h * 128 + e];
            cs += b * W_g[h * 128 + 64 + e];
        }
        c_dst[h] = cd;
        c_src[h] = cs;
    }
}

// ---------------- node transform: hh = relu(h@W_in+b), gd/gs ----------------
__global__ __launch_bounds__(256) void node_kernel(
    const float* __restrict__ hin,
    const float* __restrict__ W_in, const float* __restrict__ b_in,
    const float* __restrict__ v_dst, const float* __restrict__ v_src,
    const float* __restrict__ c_dst, const float* __restrict__ c_src,
    float* __restrict__ hh, float* __restrict__ gd, float* __restrict__ gs) {
    __shared__ float lh[TILE_N][IN_DIM];   // 16 KB
    int t = threadIdx.x;
    int n0 = blockIdx.x * TILE_N;
    #pragma unroll
    for (int i = 0; i < TILE_N; ++i)
        lh[i][t] = hin[(size_t)(n0 + i) * IN_DIM + t];
    __syncthreads();

    float acc[TILE_N];
    float bb = b_in[t];
    #pragma unroll
    for (int i = 0; i < TILE_N; ++i) acc[i] = bb;

    for (int k = 0; k < IN_DIM; k += 4) {
        float w0 = W_in[(k + 0) * HD + t];
        float w1 = W_in[(k + 1) * HD + t];
        float w2 = W_in[(k + 2) * HD + t];
        float w3 = W_in[(k + 3) * HD + t];
        #pragma unroll
        for (int i = 0; i < TILE_N; ++i) {
            float4 hv = *(const float4*)&lh[i][k];
            acc[i] += hv.x * w0 + hv.y * w1 + hv.z * w2 + hv.w * w3;
        }
    }

    #pragma unroll
    for (int i = 0; i < TILE_N; ++i) {
        acc[i] = fmaxf(acc[i], 0.f);
        hh[(size_t)(n0 + i) * HD + t] = acc[i];
    }

    // gd/gs: t = head*64 + d; wave w handles head w
    int head = t >> 6, lane = t & 63;
    float vd = v_dst[t];
    float vs = v_src[t];
    float cd = c_dst[head], cs = c_src[head];
    for (int i = 0; i < TILE_N; ++i) {
        float pd = acc[i] * vd;
        float ps = acc[i] * vs;
        #pragma unroll
        for (int off = 32; off; off >>= 1) {
            pd += __shfl_xor(pd, off, 64);
            ps += __shfl_xor(ps, off, 64);
        }
        if (lane == 0) {
            gd[(n0 + i) * HEADS + head] = pd + cd;
            gs[(n0 + i) * HEADS + head] = ps + cs;
        }
    }
}

// ---------------- edge scatter: z[dst] += hh[src] * alpha ----------------
__global__ __launch_bounds__(256) void edge_kernel(
    const int* __restrict__ src, const int* __restrict__ dst,
    const float* __restrict__ dnorm, const float* __restrict__ b_g,
    const float* __restrict__ hh, const float* __restrict__ gd,
    const float* __restrict__ gs, float* __restrict__ z) {
    int e = blockIdx.x;
    int t = threadIdx.x;
    int head = t >> 6;
    int s = src[e], dd = dst[e];
    float _h = gd[dd * HEADS + head] + gs[s * HEADS + head] + b_g[head];
    float g = _h > 0.f ? _h : -P_L * _h;
    float alpha = g * dnorm[dd] * dnorm[s];
    float val = hh[(size_t)s * HD + t] * alpha;
    atomicAdd(&z[(size_t)dd * HD + t], val);
}

// ---------------- output GEMM: out = z @ W_out + b_out ----------------
__global__ __launch_bounds__(256) void out_kernel(
    const float* __restrict__ z,
    const float* __restrict__ W_out, const float* __restrict__ b_out,
    float* __restrict__ out) {
    __shared__ float lw[HD][OUT_DIM];   // 64 KB
    int t = threadIdx.x;
    for (int i = t; i < HD * OUT_DIM; i += 256)
        ((float*)lw)[i] = W_out[i];
    __syncthreads();
    int j = t & 63, nl = t >> 6;
    int n = blockIdx.x * CN + nl;
    float acc = b_out[j];
    const float* zr = z + (size_t)n * HD;
    for (int k = 0; k < HD; k += 4) {
        float4 zv = *(const float4*)&zr[k];
        acc += zv.x * lw[k][j] + zv.y * lw[k + 1][j] + zv.z * lw[k + 2][j] + zv.w * lw[k + 3][j];
    }
    out[(size_t)n * OUT_DIM + j] = acc;
}

extern "C" void kernel_launch(void* const* d_in, const int* in_sizes, int n_in,
                              void* d_out, int out_size, void* d_ws, size_t ws_size,
                              hipStream_t stream) {
    const float* h     = (const float*)d_in[0];
    const int*   src   = (const int*)d_in[1];
    const int*   dst   = (const int*)d_in[2];
    const float* dnorm = (const float*)d_in[3];
    const float* W_in  = (const float*)d_in[4];
    const float* b_in  = (const float*)d_in[5];
    const float* W_att = (const float*)d_in[6];
    const float* b_att = (const float*)d_in[7];
    const float* W_g   = (const float*)d_in[8];
    const float* b_g   = (const float*)d_in[9];
    const float* W_out = (const float*)d_in[10];
    const float* b_out = (const float*)d_in[11];
    float* out = (float*)d_out;

    float* ws    = (float*)d_ws;
    float* hh    = ws;                                   // N*256
    float* z     = hh + (size_t)N_NODES * HD;            // N*256
    float* gd    = z + (size_t)N_NODES * HD;             // N*4
    float* gs    = gd + (size_t)N_NODES * HEADS;         // N*4
    float* v_dst = gs + (size_t)N_NODES * HEADS;         // 256
    float* v_src = v_dst + 256;                          // 256
    float* c_dst = v_src + 256;                          // 4
    float* c_src = c_dst + 4;                            // 4

    hipMemsetAsync(z, 0, (size_t)N_NODES * HD * sizeof(float), stream);
    precompute_kernel<<<1, 256, 0, stream>>>(W_att, b_att, W_g, v_dst, v_src, c_dst, c_src);
    node_kernel<<<N_NODES / TILE_N, 256, 0, stream>>>(h, W_in, b_in, v_dst, v_src,
                                                      c_dst, c_src, hh, gd, gs);
    edge_kernel<<<N_EDGES, 256, 0, stream>>>(src, dst, dnorm, b_g, hh, gd, gs, z);
    out_kernel<<<N_NODES / CN, 256, 0, stream>>>(z, W_out, b_out, out);
}

// Round 2
// 668.720 us; speedup vs baseline: 1.4852x; 1.4852x over previous
//
#include <hip/hip_runtime.h>

#define N_NODES 50000
#define N_EDGES 800000
#define IN_DIM 256
#define OUT_DIM 64
#define HEADS 4
#define HD 256          // HEADS*OUT_DIM
#define P_L 0.1f
#define TILE_N 16
#define CN 4
#define CAP 64          // per-node edge bucket capacity (expected max deg ~40)
#define OVCAP 4096      // overflow list capacity

// ---------------- precompute: fold W_att/b_att into W_g ----------------
__global__ __launch_bounds__(256) void precompute_kernel(
    const float* __restrict__ W_att, const float* __restrict__ b_att,
    const float* __restrict__ W_g,
    float* __restrict__ v_dst, float* __restrict__ v_src,
    float* __restrict__ c_dst, float* __restrict__ c_src) {
    int t = threadIdx.x;          // 0..255
    int h = t >> 6, dd = t & 63;
    float sd = 0.f, ss = 0.f;
    for (int e = 0; e < 64; ++e) {
        float w = W_att[h * 4096 + dd * 64 + e];
        sd += w * W_g[h * 128 + e];
        ss += w * W_g[h * 128 + 64 + e];
    }
    v_dst[t] = sd;
    v_src[t] = ss;
    if (dd == 0) {
        float cd = 0.f, cs = 0.f;
        for (int e = 0; e < 64; ++e) {
            float b = b_att[h * 64 + e];
            cd += b * W_g[h * 128 + e];
            cs += b * W_g[h * 128 + 64 + e];
        }
        c_dst[h] = cd;
        c_src[h] = cs;
    }
}

// ---------------- node transform: hh = relu(h@W_in+b), gd/gs ----------------
__global__ __launch_bounds__(256) void node_kernel(
    const float* __restrict__ hin,
    const float* __restrict__ W_in, const float* __restrict__ b_in,
    const float* __restrict__ v_dst, const float* __restrict__ v_src,
    const float* __restrict__ c_dst, const float* __restrict__ c_src,
    float* __restrict__ hh, float* __restrict__ gd, float* __restrict__ gs) {
    __shared__ float lh[TILE_N][IN_DIM];   // 16 KB
    int t = threadIdx.x;
    int n0 = blockIdx.x * TILE_N;
    #pragma unroll
    for (int i = 0; i < TILE_N; ++i)
        lh[i][t] = hin[(size_t)(n0 + i) * IN_DIM + t];
    __syncthreads();

    float acc[TILE_N];
    float bb = b_in[t];
    #pragma unroll
    for (int i = 0; i < TILE_N; ++i) acc[i] = bb;

    for (int k = 0; k < IN_DIM; k += 4) {
        float w0 = W_in[(k + 0) * HD + t];
        float w1 = W_in[(k + 1) * HD + t];
        float w2 = W_in[(k + 2) * HD + t];
        float w3 = W_in[(k + 3) * HD + t];
        #pragma unroll
        for (int i = 0; i < TILE_N; ++i) {
            float4 hv = *(const float4*)&lh[i][k];
            acc[i] += hv.x * w0 + hv.y * w1 + hv.z * w2 + hv.w * w3;
        }
    }

    #pragma unroll
    for (int i = 0; i < TILE_N; ++i) {
        acc[i] = fmaxf(acc[i], 0.f);
        hh[(size_t)(n0 + i) * HD + t] = acc[i];
    }

    // gd/gs: t = head*64 + d; wave w handles head w
    int head = t >> 6, lane = t & 63;
    float vd = v_dst[t];
    float vs = v_src[t];
    float cd = c_dst[head], cs = c_src[head];
    for (int i = 0; i < TILE_N; ++i) {
        float pd = acc[i] * vd;
        float ps = acc[i] * vs;
        #pragma unroll
        for (int off = 32; off; off >>= 1) {
            pd += __shfl_xor(pd, off, 64);
            ps += __shfl_xor(ps, off, 64);
        }
        if (lane == 0) {
            gd[(n0 + i) * HEADS + head] = pd + cd;
            gs[(n0 + i) * HEADS + head] = ps + cs;
        }
    }
}

// ---------------- bucket fill: group edge ids by dst ----------------
__global__ __launch_bounds__(256) void fill_kernel(
    const int* __restrict__ dst, int* __restrict__ cursor,
    int* __restrict__ edge_ids, int* __restrict__ ov_list,
    int* __restrict__ ov_count) {
    int e = blockIdx.x * 256 + threadIdx.x;
    if (e >= N_EDGES) return;
    int n = dst[e];
    int pos = atomicAdd(&cursor[n], 1);
    if (pos < CAP) {
        edge_ids[(size_t)n * CAP + pos] = e;
    } else {
        int oi = atomicAdd(ov_count, 1);
        if (oi < OVCAP) ov_list[oi] = e;
    }
}

// ---------------- gather aggregation: z[n] = sum over in-edges ----------------
__global__ __launch_bounds__(256) void agg_kernel(
    const int* __restrict__ edge_ids, const int* __restrict__ cursor,
    const int* __restrict__ src,
    const float* __restrict__ dnorm, const float* __restrict__ b_g,
    const float* __restrict__ hh, const float* __restrict__ gd,
    const float* __restrict__ gs, float* __restrict__ z) {
    int n = blockIdx.x;
    int t = threadIdx.x;
    int head = t >> 6;
    int deg = cursor[n];
    if (deg > CAP) deg = CAP;
    float dn = dnorm[n];
    float gdn = gd[n * HEADS + head] + b_g[head];
    const int* eids = edge_ids + (size_t)n * CAP;
    float acc = 0.f;
    for (int i = 0; i < deg; ++i) {
        int e = eids[i];
        int s = src[e];
        float _h = gdn + gs[s * HEADS + head];
        float g = _h > 0.f ? _h : -P_L * _h;
        float alpha = g * dn * dnorm[s];
        acc += hh[(size_t)s * HD + t] * alpha;
    }
    z[(size_t)n * HD + t] = acc;
}

// ---------------- overflow fixup (almost always empty) ----------------
__global__ __launch_bounds__(256) void fixup_kernel(
    const int* __restrict__ ov_list, const int* __restrict__ ov_count,
    const int* __restrict__ src, const int* __restrict__ dst,
    const float* __restrict__ dnorm, const float* __restrict__ b_g,
    const float* __restrict__ hh, const float* __restrict__ gd,
    const float* __restrict__ gs, float* __restrict__ z) {
    int cnt = *ov_count;
    if (cnt > OVCAP) cnt = OVCAP;
    int t = threadIdx.x;
    int head = t >> 6;
    for (int i = blockIdx.x; i < cnt; i += gridDim.x) {
        int e = ov_list[i];
        int s = src[e], dd = dst[e];
        float _h = gd[dd * HEADS + head] + gs[s * HEADS + head] + b_g[head];
        float g = _h > 0.f ? _h : -P_L * _h;
        float alpha = g * dnorm[dd] * dnorm[s];
        atomicAdd(&z[(size_t)dd * HD + t], hh[(size_t)s * HD + t] * alpha);
    }
}

// ---------------- output GEMM: out = z @ W_out + b_out ----------------
__global__ __launch_bounds__(256) void out_kernel(
    const float* __restrict__ z,
    const float* __restrict__ W_out, const float* __restrict__ b_out,
    float* __restrict__ out) {
    __shared__ float lw[HD][OUT_DIM];   // 64 KB
    int t = threadIdx.x;
    for (int i = t; i < HD * OUT_DIM; i += 256)
        ((float*)lw)[i] = W_out[i];
    __syncthreads();
    int j = t & 63, nl = t >> 6;
    int n = blockIdx.x * CN + nl;
    float acc = b_out[j];
    const float* zr = z + (size_t)n * HD;
    for (int k = 0; k < HD; k += 4) {
        float4 zv = *(const float4*)&zr[k];
        acc += zv.x * lw[k][j] + zv.y * lw[k + 1][j] + zv.z * lw[k + 2][j] + zv.w * lw[k + 3][j];
    }
    out[(size_t)n * OUT_DIM + j] = acc;
}

extern "C" void kernel_launch(void* const* d_in, const int* in_sizes, int n_in,
                              void* d_out, int out_size, void* d_ws, size_t ws_size,
                              hipStream_t stream) {
    const float* h     = (const float*)d_in[0];
    const int*   src   = (const int*)d_in[1];
    const int*   dst   = (const int*)d_in[2];
    const float* dnorm = (const float*)d_in[3];
    const float* W_in  = (const float*)d_in[4];
    const float* b_in  = (const float*)d_in[5];
    const float* W_att = (const float*)d_in[6];
    const float* b_att = (const float*)d_in[7];
    const float* W_g   = (const float*)d_in[8];
    const float* b_g   = (const float*)d_in[9];
    const float* W_out = (const float*)d_in[10];
    const float* b_out = (const float*)d_in[11];
    float* out = (float*)d_out;

    float* ws    = (float*)d_ws;
    float* hh    = ws;                                   // N*256
    float* z     = hh + (size_t)N_NODES * HD;            // N*256
    float* gd    = z + (size_t)N_NODES * HD;             // N*4
    float* gs    = gd + (size_t)N_NODES * HEADS;         // N*4
    float* v_dst = gs + (size_t)N_NODES * HEADS;         // 256
    float* v_src = v_dst + 256;                          // 256
    float* c_dst = v_src + 256;                          // 4
    float* c_src = c_dst + 4;                            // 4
    int*   cursor   = (int*)(c_src + 4);                 // N
    int*   ov_count = cursor + N_NODES;                  // 1
    int*   ov_list  = ov_count + 1;                      // OVCAP
    int*   edge_ids = ov_list + OVCAP;                   // N*CAP (12.8 MB)

    hipMemsetAsync(cursor, 0, (size_t)N_NODES * sizeof(int), stream);
    hipMemsetAsync(ov_count, 0, sizeof(int), stream);

    precompute_kernel<<<1, 256, 0, stream>>>(W_att, b_att, W_g, v_dst, v_src, c_dst, c_src);
    node_kernel<<<N_NODES / TILE_N, 256, 0, stream>>>(h, W_in, b_in, v_dst, v_src,
                                                      c_dst, c_src, hh, gd, gs);
    fill_kernel<<<(N_EDGES + 255) / 256, 256, 0, stream>>>(dst, cursor, edge_ids,
                                                           ov_list, ov_count);
    agg_kernel<<<N_NODES, 256, 0, stream>>>(edge_ids, cursor, src, dnorm, b_g,
                                            hh, gd, gs, z);
    fixup_kernel<<<16, 256, 0, stream>>>(ov_list, ov_count, src, dst, dnorm, b_g,
                                         hh, gd, gs, z);
    out_kernel<<<N_NODES / CN, 256, 0, stream>>>(z, W_out, b_out, out);
}

// Round 3
// 502.207 us; speedup vs baseline: 1.9777x; 1.3316x over previous
//
#include <hip/hip_runtime.h>

#define N_NODES 50000
#define N_EDGES 800000
#define IN_DIM 256
#define OUT_DIM 64
#define HEADS 4
#define HD 256          // HEADS*OUT_DIM
#define P_L 0.1f
#define TILE_N 16
#define CN 4
#define CAP 64          // per-node edge bucket capacity (expected max deg ~43)
#define OVCAP 4096      // overflow list capacity

// ---------------- precompute: fold W_att/b_att into W_g ----------------
__global__ __launch_bounds__(256) void precompute_kernel(
    const float* __restrict__ W_att, const float* __restrict__ b_att,
    const float* __restrict__ W_g,
    float* __restrict__ v_dst, float* __restrict__ v_src,
    float* __restrict__ c_dst, float* __restrict__ c_src) {
    int t = threadIdx.x;          // 0..255
    int h = t >> 6, dd = t & 63;
    float sd = 0.f, ss = 0.f;
    for (int e = 0; e < 64; ++e) {
        float w = W_att[h * 4096 + dd * 64 + e];
        sd += w * W_g[h * 128 + e];
        ss += w * W_g[h * 128 + 64 + e];
    }
    v_dst[t] = sd;
    v_src[t] = ss;
    if (dd == 0) {
        float cd = 0.f, cs = 0.f;
        for (int e = 0; e < 64; ++e) {
            float b = b_att[h * 64 + e];
            cd += b * W_g[h * 128 + e];
            cs += b * W_g[h * 128 + 64 + e];
        }
        c_dst[h] = cd;
        c_src[h] = cs;
    }
}

// ---------------- node transform: hh = relu(h@W_in+b), gd/gs ----------------
__global__ __launch_bounds__(256) void node_kernel(
    const float* __restrict__ hin,
    const float* __restrict__ W_in, const float* __restrict__ b_in,
    const float* __restrict__ v_dst, const float* __restrict__ v_src,
    const float* __restrict__ c_dst, const float* __restrict__ c_src,
    float* __restrict__ hh, float* __restrict__ gd, float* __restrict__ gs) {
    __shared__ float lh[TILE_N][IN_DIM];   // 16 KB
    int t = threadIdx.x;
    int n0 = blockIdx.x * TILE_N;
    #pragma unroll
    for (int i = 0; i < TILE_N; ++i)
        lh[i][t] = hin[(size_t)(n0 + i) * IN_DIM + t];
    __syncthreads();

    float acc[TILE_N];
    float bb = b_in[t];
    #pragma unroll
    for (int i = 0; i < TILE_N; ++i) acc[i] = bb;

    for (int k = 0; k < IN_DIM; k += 4) {
        float w0 = W_in[(k + 0) * HD + t];
        float w1 = W_in[(k + 1) * HD + t];
        float w2 = W_in[(k + 2) * HD + t];
        float w3 = W_in[(k + 3) * HD + t];
        #pragma unroll
        for (int i = 0; i < TILE_N; ++i) {
            float4 hv = *(const float4*)&lh[i][k];
            acc[i] += hv.x * w0 + hv.y * w1 + hv.z * w2 + hv.w * w3;
        }
    }

    #pragma unroll
    for (int i = 0; i < TILE_N; ++i) {
        acc[i] = fmaxf(acc[i], 0.f);
        hh[(size_t)(n0 + i) * HD + t] = acc[i];
    }

    // gd/gs: t = head*64 + d; wave w handles head w
    int head = t >> 6, lane = t & 63;
    float vd = v_dst[t];
    float vs = v_src[t];
    float cd = c_dst[head], cs = c_src[head];
    for (int i = 0; i < TILE_N; ++i) {
        float pd = acc[i] * vd;
        float ps = acc[i] * vs;
        #pragma unroll
        for (int off = 32; off; off >>= 1) {
            pd += __shfl_xor(pd, off, 64);
            ps += __shfl_xor(ps, off, 64);
        }
        if (lane == 0) {
            gd[(n0 + i) * HEADS + head] = pd + cd;
            gs[(n0 + i) * HEADS + head] = ps + cs;
        }
    }
}

// ---------------- bucket fill: group SRC node ids by dst ----------------
__global__ __launch_bounds__(256) void fill_kernel(
    const int* __restrict__ src, const int* __restrict__ dst,
    int* __restrict__ cursor, int* __restrict__ bucket_src,
    int* __restrict__ ov_list, int* __restrict__ ov_count) {
    int e = blockIdx.x * 256 + threadIdx.x;
    if (e >= N_EDGES) return;
    int n = dst[e];
    int pos = atomicAdd(&cursor[n], 1);
    if (pos < CAP) {
        bucket_src[(size_t)n * CAP + pos] = src[e];
    } else {
        int oi = atomicAdd(ov_count, 1);
        if (oi < OVCAP) ov_list[oi] = e;
    }
}

// ---------------- gather aggregation: z[n] = sum over in-edges ----------------
__global__ __launch_bounds__(256) void agg_kernel(
    const int* __restrict__ bucket_src, const int* __restrict__ cursor,
    const float* __restrict__ dnorm, const float* __restrict__ b_g,
    const float* __restrict__ hh, const float* __restrict__ gd,
    const float* __restrict__ gs, float* __restrict__ z) {
    __shared__ int s_lds[CAP];
    __shared__ float alpha_lds[CAP][HEADS];
    int n = blockIdx.x;
    int t = threadIdx.x;
    int deg = cursor[n];
    if (deg > CAP) deg = CAP;
    float dn = dnorm[n];

    // phase 1: per-edge alphas in parallel. thread t = edge (t>>2), head (t&3).
    int ei = t >> 2, hd = t & 3;
    if (ei < deg) {
        int s = bucket_src[(size_t)n * CAP + ei];
        if (hd == 0) s_lds[ei] = s;
        float _h = gd[n * HEADS + hd] + gs[s * HEADS + hd] + b_g[hd];
        float g = _h > 0.f ? _h : -P_L * _h;
        alpha_lds[ei][hd] = g * dn * dnorm[s];
    }
    __syncthreads();

    // phase 2: unrolled gather, 4 independent hh loads in flight
    int head = t >> 6;
    float acc = 0.f;
    int i = 0;
    for (; i + 4 <= deg; i += 4) {
        int s0 = s_lds[i + 0], s1 = s_lds[i + 1];
        int s2 = s_lds[i + 2], s3 = s_lds[i + 3];
        float a0 = alpha_lds[i + 0][head], a1 = alpha_lds[i + 1][head];
        float a2 = alpha_lds[i + 2][head], a3 = alpha_lds[i + 3][head];
        float h0 = hh[(size_t)s0 * HD + t];
        float h1 = hh[(size_t)s1 * HD + t];
        float h2 = hh[(size_t)s2 * HD + t];
        float h3 = hh[(size_t)s3 * HD + t];
        acc += h0 * a0 + h1 * a1 + h2 * a2 + h3 * a3;
    }
    for (; i < deg; ++i) {
        acc += hh[(size_t)s_lds[i] * HD + t] * alpha_lds[i][head];
    }
    z[(size_t)n * HD + t] = acc;
}

// ---------------- overflow fixup (almost always empty) ----------------
__global__ __launch_bounds__(256) void fixup_kernel(
    const int* __restrict__ ov_list, const int* __restrict__ ov_count,
    const int* __restrict__ src, const int* __restrict__ dst,
    const float* __restrict__ dnorm, const float* __restrict__ b_g,
    const float* __restrict__ hh, const float* __restrict__ gd,
    const float* __restrict__ gs, float* __restrict__ z) {
    int cnt = *ov_count;
    if (cnt > OVCAP) cnt = OVCAP;
    int t = threadIdx.x;
    int head = t >> 6;
    for (int i = blockIdx.x; i < cnt; i += gridDim.x) {
        int e = ov_list[i];
        int s = src[e], dd = dst[e];
        float _h = gd[dd * HEADS + head] + gs[s * HEADS + head] + b_g[head];
        float g = _h > 0.f ? _h : -P_L * _h;
        float alpha = g * dnorm[dd] * dnorm[s];
        atomicAdd(&z[(size_t)dd * HD + t], hh[(size_t)s * HD + t] * alpha);
    }
}

// ---------------- output GEMM: out = z @ W_out + b_out ----------------
__global__ __launch_bounds__(256) void out_kernel(
    const float* __restrict__ z,
    const float* __restrict__ W_out, const float* __restrict__ b_out,
    float* __restrict__ out) {
    __shared__ float lw[HD][OUT_DIM];   // 64 KB
    int t = threadIdx.x;
    for (int i = t; i < HD * OUT_DIM; i += 256)
        ((float*)lw)[i] = W_out[i];
    __syncthreads();
    int j = t & 63, nl = t >> 6;
    int n = blockIdx.x * CN + nl;
    float acc = b_out[j];
    const float* zr = z + (size_t)n * HD;
    for (int k = 0; k < HD; k += 4) {
        float4 zv = *(const float4*)&zr[k];
        acc += zv.x * lw[k][j] + zv.y * lw[k + 1][j] + zv.z * lw[k + 2][j] + zv.w * lw[k + 3][j];
    }
    out[(size_t)n * OUT_DIM + j] = acc;
}

extern "C" void kernel_launch(void* const* d_in, const int* in_sizes, int n_in,
                              void* d_out, int out_size, void* d_ws, size_t ws_size,
                              hipStream_t stream) {
    const float* h     = (const float*)d_in[0];
    const int*   src   = (const int*)d_in[1];
    const int*   dst   = (const int*)d_in[2];
    const float* dnorm = (const float*)d_in[3];
    const float* W_in  = (const float*)d_in[4];
    const float* b_in  = (const float*)d_in[5];
    const float* W_att = (const float*)d_in[6];
    const float* b_att = (const float*)d_in[7];
    const float* W_g   = (const float*)d_in[8];
    const float* b_g   = (const float*)d_in[9];
    const float* W_out = (const float*)d_in[10];
    const float* b_out = (const float*)d_in[11];
    float* out = (float*)d_out;

    float* ws    = (float*)d_ws;
    float* hh    = ws;                                   // N*256
    float* z     = hh + (size_t)N_NODES * HD;            // N*256
    float* gd    = z + (size_t)N_NODES * HD;             // N*4
    float* gs    = gd + (size_t)N_NODES * HEADS;         // N*4
    float* v_dst = gs + (size_t)N_NODES * HEADS;         // 256
    float* v_src = v_dst + 256;                          // 256
    float* c_dst = v_src + 256;                          // 4
    float* c_src = c_dst + 4;                            // 4
    int*   cursor     = (int*)(c_src + 4);               // N
    int*   ov_count   = cursor + N_NODES;                // 1
    int*   ov_list    = ov_count + 1;                    // OVCAP
    int*   bucket_src = ov_list + OVCAP;                 // N*CAP (12.8 MB)

    hipMemsetAsync(cursor, 0, (size_t)N_NODES * sizeof(int), stream);
    hipMemsetAsync(ov_count, 0, sizeof(int), stream);

    precompute_kernel<<<1, 256, 0, stream>>>(W_att, b_att, W_g, v_dst, v_src, c_dst, c_src);
    fill_kernel<<<(N_EDGES + 255) / 256, 256, 0, stream>>>(src, dst, cursor, bucket_src,
                                                           ov_list, ov_count);
    node_kernel<<<N_NODES / TILE_N, 256, 0, stream>>>(h, W_in, b_in, v_dst, v_src,
                                                      c_dst, c_src, hh, gd, gs);
    agg_kernel<<<N_NODES, 256, 0, stream>>>(bucket_src, cursor, dnorm, b_g,
                                            hh, gd, gs, z);
    fixup_kernel<<<16, 256, 0, stream>>>(ov_list, ov_count, src, dst, dnorm, b_g,
                                         hh, gd, gs, z);
    out_kernel<<<N_NODES / CN, 256, 0, stream>>>(z, W_out, b_out, out);
}